// Round 2
// baseline (1502.733 us; speedup 1.0000x reference)
//
#include <hip/hip_runtime.h>
#include <stdint.h>

#define N_ROWS 32768
#define K_CB   8192
#define D_DIM  512
#define TAU    0.07f
#define BM     128
#define BK     32
#define NKT    256

typedef __attribute__((ext_vector_type(8))) short bf16x8;
typedef __attribute__((ext_vector_type(4))) float f32x4;

__device__ __forceinline__ unsigned short f2bf(float f) {
    unsigned u = __builtin_bit_cast(unsigned, f);
    u += 0x7FFFu + ((u >> 16) & 1u);          // round-to-nearest-even
    return (unsigned short)(u >> 16);
}

__device__ __forceinline__ void glds16(const unsigned short* g, unsigned short* l) {
    __builtin_amdgcn_global_load_lds(
        (const __attribute__((address_space(1))) unsigned int*)g,
        (__attribute__((address_space(3))) unsigned int*)l, 16, 0, 0);
}

__device__ __forceinline__ unsigned cvtpk(float a, float b) {
    unsigned r;
    asm("v_cvt_pk_bf16_f32 %0, %1, %2" : "=v"(r) : "v"(a), "v"(b));
    return r;
}

// a's lanes 32-63 <-> b's lanes 0-31  (validated on HW in prior round)
__device__ __forceinline__ void pl32swap(unsigned& a, unsigned& b) {
    asm volatile("v_permlane32_swap_b32 %0, %1" : "+v"(a), "+v"(b));
}
// a's lanes 16-31 <-> b's lanes 0-15, a's 48-63 <-> b's 32-47
__device__ __forceinline__ void pl16swap(unsigned& a, unsigned& b) {
    asm volatile("v_permlane16_swap_b32 %0, %1" : "+v"(a), "+v"(b));
}
__device__ __forceinline__ void pl32swapf(float& a, float& b) {
    asm volatile("v_permlane32_swap_b32 %0, %1" : "+v"(a), "+v"(b));
}
__device__ __forceinline__ void pl16swapf(float& a, float& b) {
    asm volatile("v_permlane16_swap_b32 %0, %1" : "+v"(a), "+v"(b));
}

// codebook fp32 [K][512] -> two pre-swizzled bf16 arrays of 16B chunks per 32-row tile:
//  rm_sw: chunk c = cbl*64 + (dc ^ (cbl&7))        holds C[tile cb=cbl][d = dc*8 .. +7]
//  t_sw : chunk c = (d*4 + cbc) ^ ((d>>1)&7)       holds C[tile cb=cbc*8+e][d], e=0..7
__global__ __launch_bounds__(512) void prep_codebook(const float* __restrict__ cb,
                                                     unsigned short* __restrict__ rm_sw,
                                                     unsigned short* __restrict__ t_sw) {
    __shared__ unsigned short tile[32 * 512];     // row-major [cbl][d]
    const int j = blockIdx.x, t = threadIdx.x;
    const float2* src = (const float2*)(cb + (size_t)j * (BK * D_DIM));
    unsigned* t32 = (unsigned*)tile;
    #pragma unroll
    for (int it = 0; it < 16; ++it) {
        int e2 = it * 512 + t;
        float2 v = src[e2];
        t32[e2] = (unsigned)f2bf(v.x) | ((unsigned)f2bf(v.y) << 16);
    }
    __syncthreads();
    uint4* rmd = (uint4*)rm_sw + (size_t)j * 2048;
    uint4* twd = (uint4*)t_sw + (size_t)j * 2048;
    #pragma unroll
    for (int it = 0; it < 4; ++it) {
        int L = it * 512 + t;
        int cbl = L >> 6, dc = L & 63;
        int c = cbl * 64 + (dc ^ (cbl & 7));
        rmd[c] = *(const uint4*)&tile[cbl * 512 + dc * 8];
    }
    #pragma unroll
    for (int it = 0; it < 4; ++it) {
        int M = it * 512 + t;
        int d = M >> 2, cbc = M & 3;
        int c = (d * 4 + cbc) ^ ((d >> 1) & 7);
        unsigned short tmp[8];
        #pragma unroll
        for (int e = 0; e < 8; ++e) tmp[e] = tile[(cbc * 8 + e) * 512 + d];
        twd[c] = *(const uint4*)tmp;
    }
}

__global__ __launch_bounds__(512, 2) void cbmap_main(const float* __restrict__ x,
                                                     const unsigned short* __restrict__ rm_sw,
                                                     const unsigned short* __restrict__ t_sw,
                                                     float* __restrict__ out) {
    __shared__ unsigned short s_rm[2][16384];   // 2 × 32 KB, swizzled cb-major tile
    __shared__ unsigned short s_ct[2][16384];   // 2 × 32 KB, swizzled d-major tile
    __shared__ unsigned short s_px[8][512];     // 8 × 1 KB, P-fragment exchange
    __shared__ float s_ds[128];                 // softmax denominators

    const int tid = threadIdx.x;
    const int w = tid >> 6, lane = tid & 63, l15 = lane & 15, q = lane >> 4;
    const int pairA = w >> 1, dhalf = w & 1;
    const int srow0 = blockIdx.x * BM + w * 16;   // this wave's 16 S-rows

    // ---- prologue: L2-normalize own rows, fold 1/TAU, A-fragments in regs
    const float* xrow = x + (size_t)(srow0 + l15) * D_DIM + q * 8;
    float4 va[16], vb[16];
    float ss = 0.f;
    #pragma unroll
    for (int k = 0; k < 16; ++k) {
        va[k] = *(const float4*)(xrow + k * 32);
        vb[k] = *(const float4*)(xrow + k * 32 + 4);
        ss += va[k].x*va[k].x + va[k].y*va[k].y + va[k].z*va[k].z + va[k].w*va[k].w;
        ss += vb[k].x*vb[k].x + vb[k].y*vb[k].y + vb[k].z*vb[k].z + vb[k].w*vb[k].w;
    }
    ss += __shfl_xor(ss, 16, 64);
    ss += __shfl_xor(ss, 32, 64);
    const float scale = 1.0f / (fmaxf(sqrtf(ss), 1e-12f) * TAU);
    bf16x8 afrag[16];
    #pragma unroll
    for (int k = 0; k < 16; ++k) {
        bf16x8 f;
        f[0] = (short)f2bf(va[k].x * scale); f[1] = (short)f2bf(va[k].y * scale);
        f[2] = (short)f2bf(va[k].z * scale); f[3] = (short)f2bf(va[k].w * scale);
        f[4] = (short)f2bf(vb[k].x * scale); f[5] = (short)f2bf(vb[k].y * scale);
        f[6] = (short)f2bf(vb[k].z * scale); f[7] = (short)f2bf(vb[k].w * scale);
        afrag[k] = f;
    }

    f32x4 acc[2][16];
    #pragma unroll
    for (int mt = 0; mt < 2; ++mt)
        #pragma unroll
        for (int nt = 0; nt < 16; ++nt) acc[mt][nt] = (f32x4){0.f,0.f,0.f,0.f};
    float dsum = 0.f;

    // ---- preload tile 0 -> buffer 0 (async global->LDS, 16B/lane)
    #pragma unroll
    for (int k = 0; k < 4; ++k) {
        glds16(rm_sw + (size_t)(k * 512 + tid) * 8, &s_rm[0][(k * 512 + tid) * 8]);
        glds16(t_sw  + (size_t)(k * 512 + tid) * 8, &s_ct[0][(k * 512 + tid) * 8]);
    }
    __syncthreads();

    const int pxc = (l15 * 4 + (q ^ ((l15 >> 1) & 3))) * 8;  // swizzled px chunk (u16 offset)
    const int swz = l15 & 7;

    for (int j = 0; j < NKT; ++j) {
        const int p = j & 1;
        const size_t nb = (size_t)((j + 1) & (NKT - 1)) * 16384;
        // prefetch next tile into the other buffer; drains at the next barrier
        #pragma unroll
        for (int k = 0; k < 4; ++k) {
            glds16(rm_sw + nb + (size_t)(k * 512 + tid) * 8, &s_rm[p ^ 1][(k * 512 + tid) * 8]);
            glds16(t_sw  + nb + (size_t)(k * 512 + tid) * 8, &s_ct[p ^ 1][(k * 512 + tid) * 8]);
        }

        // ---- S^T = C_tile · x_n^T  (A = cb-frag from LDS, B = x-frag regs)
        f32x4 s0 = (f32x4){0.f,0.f,0.f,0.f};
        f32x4 s1 = (f32x4){0.f,0.f,0.f,0.f};
        const unsigned short* srm = s_rm[p];
        #pragma unroll
        for (int kt = 0; kt < 16; ++kt) {
            int dc = (kt * 4 + q) ^ swz;
            bf16x8 bb0 = *(const bf16x8*)&srm[(l15 * 64 + dc) * 8];
            bf16x8 bb1 = *(const bf16x8*)&srm[((16 + l15) * 64 + dc) * 8];
            s0 = __builtin_amdgcn_mfma_f32_16x16x32_bf16(bb0, afrag[kt], s0, 0, 0, 0);
            s1 = __builtin_amdgcn_mfma_f32_16x16x32_bf16(bb1, afrag[kt], s1, 0, 0, 0);
        }

        // ---- P = exp(S^T): lane(q,l15) holds P[row l15][cb 4q+r] (s0) and [16+4q+r] (s1)
        const float e0 = __expf(s0[0]), e1 = __expf(s0[1]), e2 = __expf(s0[2]), e3 = __expf(s0[3]);
        const float f0 = __expf(s1[0]), f1 = __expf(s1[1]), f2 = __expf(s1[2]), f3 = __expf(s1[3]);
        float loc = ((e0 + e1) + (e2 + e3)) + ((f0 + f1) + (f2 + f3));
        // row-sum across quads without LDS: xor16 then xor32 via permlane swaps
        float t16 = loc;
        pl16swapf(loc, t16); loc += t16;
        float t32 = loc;
        pl32swapf(loc, t32); loc += t32;
        dsum += loc;          // full row-l15 sum for this tile (replicated over quads)

        // ---- in-register transpose to PV A-layout: lane(q,l15) <- P[l15][8q+j], j=0..7
        //  A0,A1 = packed s0 cols (4q,4q+1),(4q+2,4q+3); B0,B1 = packed s1 cols
        //  {w0,w2} = pl16swap(pl32swap(A0,B0)), {w1,w3} likewise  -> apv = {w0,w1,w2,w3}
        unsigned A0 = cvtpk(e0, e1), A1 = cvtpk(e2, e3);
        unsigned B0 = cvtpk(f0, f1), B1 = cvtpk(f2, f3);
        pl32swap(A0, B0); pl32swap(A1, B1);
        pl16swap(A0, B0); pl16swap(A1, B1);
        uint4 apv; apv.x = A0; apv.y = A1; apv.z = B0; apv.w = B1;
        *(uint4*)&s_px[w][pxc] = apv;                     // partner will read this
        const bf16x8 ap_own = __builtin_bit_cast(bf16x8, apv);

        // ---- PV half 1: own rows (mt = dhalf) with in-register P-frag, BEFORE barrier
        const unsigned short* sct = s_ct[p];
        if (dhalf == 0) {
            #pragma unroll
            for (int nt = 0; nt < 16; ++nt) {
                int dd = nt * 16 + l15;
                int c = (dd * 4 + q) ^ ((dd >> 1) & 7);
                bf16x8 bt = *(const bf16x8*)&sct[c * 8];
                acc[0][nt] = __builtin_amdgcn_mfma_f32_16x16x32_bf16(ap_own, bt, acc[0][nt], 0, 0, 0);
            }
        } else {
            #pragma unroll
            for (int nt = 0; nt < 16; ++nt) {
                int dd = 256 + nt * 16 + l15;
                int c = (dd * 4 + q) ^ ((dd >> 1) & 7);
                bf16x8 bt = *(const bf16x8*)&sct[c * 8];
                acc[1][nt] = __builtin_amdgcn_mfma_f32_16x16x32_bf16(ap_own, bt, acc[1][nt], 0, 0, 0);
            }
        }
        __syncthreads();                         // B1: partner px visible + prefetch drained

        // ---- PV half 2: partner rows (mt = dhalf^1) with partner's P-frag
        const bf16x8 ap_oth = *(const bf16x8*)&s_px[w ^ 1][pxc];
        if (dhalf == 0) {
            #pragma unroll
            for (int nt = 0; nt < 16; ++nt) {
                int dd = nt * 16 + l15;
                int c = (dd * 4 + q) ^ ((dd >> 1) & 7);
                bf16x8 bt = *(const bf16x8*)&sct[c * 8];
                acc[1][nt] = __builtin_amdgcn_mfma_f32_16x16x32_bf16(ap_oth, bt, acc[1][nt], 0, 0, 0);
            }
        } else {
            #pragma unroll
            for (int nt = 0; nt < 16; ++nt) {
                int dd = 256 + nt * 16 + l15;
                int c = (dd * 4 + q) ^ ((dd >> 1) & 7);
                bf16x8 bt = *(const bf16x8*)&sct[c * 8];
                acc[0][nt] = __builtin_amdgcn_mfma_f32_16x16x32_bf16(ap_oth, bt, acc[0][nt], 0, 0, 0);
            }
        }
        __syncthreads();                         // B2: buf reads done before next overwrite
    }

    // ---- epilogue: exchange denominators, divide, store
    if (lane < 16) s_ds[w * 16 + lane] = dsum;
    __syncthreads();
    const int prow0 = pairA * 32;
    float* ob = out + ((size_t)blockIdx.x * BM + prow0) * D_DIM + dhalf * 256 + l15;
    #pragma unroll
    for (int mt = 0; mt < 2; ++mt) {
        #pragma unroll
        for (int r = 0; r < 4; ++r) {
            float inv = 1.0f / s_ds[prow0 + mt * 16 + q * 4 + r];
            #pragma unroll
            for (int nt = 0; nt < 16; ++nt) {
                ob[(size_t)(mt * 16 + q * 4 + r) * D_DIM + nt * 16] = acc[mt][nt][r] * inv;
            }
        }
    }
}

extern "C" void kernel_launch(void* const* d_in, const int* in_sizes, int n_in,
                              void* d_out, int out_size, void* d_ws, size_t ws_size,
                              hipStream_t stream) {
    const float* x  = (const float*)d_in[0];
    const float* cb = (const float*)d_in[1];
    unsigned short* rm_sw = (unsigned short*)d_ws;                       // 8 MB
    unsigned short* t_sw  = rm_sw + (size_t)K_CB * D_DIM;                // 8 MB
    float* outp = (float*)d_out;

    prep_codebook<<<NKT, 512, 0, stream>>>(cb, rm_sw, t_sw);
    cbmap_main<<<N_ROWS / BM, 512, 0, stream>>>(x, rm_sw, t_sw, outp);
}

// Round 3
// 793.670 us; speedup vs baseline: 1.8934x; 1.8934x over previous
//
#include <hip/hip_runtime.h>
#include <stdint.h>

#define N_ROWS 32768
#define K_CB   8192
#define D_DIM  512
#define TAU    0.07f
#define BM     128
#define BK     32
#define NKT    256

typedef __attribute__((ext_vector_type(8))) short bf16x8;
typedef __attribute__((ext_vector_type(4))) float f32x4;

__device__ __forceinline__ unsigned short f2bf(float f) {
    unsigned u = __builtin_bit_cast(unsigned, f);
    u += 0x7FFFu + ((u >> 16) & 1u);          // round-to-nearest-even
    return (unsigned short)(u >> 16);
}

__device__ __forceinline__ void glds16(const unsigned short* g, unsigned short* l) {
    __builtin_amdgcn_global_load_lds(
        (const __attribute__((address_space(1))) unsigned int*)g,
        (__attribute__((address_space(3))) unsigned int*)l, 16, 0, 0);
}

__device__ __forceinline__ unsigned cvtpk(float a, float b) {
    unsigned r;
    asm("v_cvt_pk_bf16_f32 %0, %1, %2" : "=v"(r) : "v"(a), "v"(b));
    return r;
}

// a's lanes 32-63 <-> b's lanes 0-31  (HW-validated round 2)
__device__ __forceinline__ void pl32swap(unsigned& a, unsigned& b) {
    asm volatile("v_permlane32_swap_b32 %0, %1" : "+v"(a), "+v"(b));
}
// a's lanes 16-31 <-> b's lanes 0-15, a's 48-63 <-> b's 32-47
__device__ __forceinline__ void pl16swap(unsigned& a, unsigned& b) {
    asm volatile("v_permlane16_swap_b32 %0, %1" : "+v"(a), "+v"(b));
}
__device__ __forceinline__ void pl32swapf(float& a, float& b) {
    asm volatile("v_permlane32_swap_b32 %0, %1" : "+v"(a), "+v"(b));
}
__device__ __forceinline__ void pl16swapf(float& a, float& b) {
    asm volatile("v_permlane16_swap_b32 %0, %1" : "+v"(a), "+v"(b));
}

// codebook fp32 [K][512] -> two pre-swizzled bf16 arrays of 16B chunks per 32-row tile:
//  rm_sw: chunk c = cbl*64 + (dc ^ (cbl&7))        holds C[tile cb=cbl][d = dc*8 .. +7]
//  t_sw : chunk c = (d*4 + cbc) ^ ((d>>1)&7)       holds C[tile cb=cbc*8+e][d], e=0..7
__global__ __launch_bounds__(512) void prep_codebook(const float* __restrict__ cb,
                                                     unsigned short* __restrict__ rm_sw,
                                                     unsigned short* __restrict__ t_sw) {
    __shared__ unsigned short tile[32 * 512];     // row-major [cbl][d]
    const int j = blockIdx.x, t = threadIdx.x;
    const float2* src = (const float2*)(cb + (size_t)j * (BK * D_DIM));
    unsigned* t32 = (unsigned*)tile;
    #pragma unroll
    for (int it = 0; it < 16; ++it) {
        int e2 = it * 512 + t;
        float2 v = src[e2];
        t32[e2] = (unsigned)f2bf(v.x) | ((unsigned)f2bf(v.y) << 16);
    }
    __syncthreads();
    uint4* rmd = (uint4*)rm_sw + (size_t)j * 2048;
    uint4* twd = (uint4*)t_sw + (size_t)j * 2048;
    #pragma unroll
    for (int it = 0; it < 4; ++it) {
        int L = it * 512 + t;
        int cbl = L >> 6, dc = L & 63;
        int c = cbl * 64 + (dc ^ (cbl & 7));
        rmd[c] = *(const uint4*)&tile[cbl * 512 + dc * 8];
    }
    #pragma unroll
    for (int it = 0; it < 4; ++it) {
        int M = it * 512 + t;
        int d = M >> 2, cbc = M & 3;
        int c = (d * 4 + cbc) ^ ((d >> 1) & 7);
        unsigned short tmp[8];
        #pragma unroll
        for (int e = 0; e < 8; ++e) tmp[e] = tile[(cbc * 8 + e) * 512 + d];
        twd[c] = *(const uint4*)tmp;
    }
}

__global__ __launch_bounds__(512, 2) void cbmap_main(const float* __restrict__ x,
                                                     const unsigned short* __restrict__ rm_sw,
                                                     const unsigned short* __restrict__ t_sw,
                                                     float* __restrict__ out) {
    __shared__ unsigned short s_rm[2][16384];   // 2 × 32 KB, swizzled cb-major tile
    __shared__ unsigned short s_ct[2][16384];   // 2 × 32 KB, swizzled d-major tile
    __shared__ unsigned short s_px[8][512];     // 8 × 1 KB, P-fragment exchange
    __shared__ float s_ds[128];                 // softmax denominators

    const int tid = threadIdx.x;
    const int w = tid >> 6, lane = tid & 63, l15 = lane & 15, q = lane >> 4;
    const int pairA = w >> 1, dhalf = w & 1;
    const int srow0 = blockIdx.x * BM + w * 16;   // this wave's 16 S-rows

    // ---- prologue: L2-normalize own rows, fold 1/TAU, A-fragments in regs
    const float* xrow = x + (size_t)(srow0 + l15) * D_DIM + q * 8;
    float4 va[16], vb[16];
    float ss = 0.f;
    #pragma unroll
    for (int k = 0; k < 16; ++k) {
        va[k] = *(const float4*)(xrow + k * 32);
        vb[k] = *(const float4*)(xrow + k * 32 + 4);
        ss += va[k].x*va[k].x + va[k].y*va[k].y + va[k].z*va[k].z + va[k].w*va[k].w;
        ss += vb[k].x*vb[k].x + vb[k].y*vb[k].y + vb[k].z*vb[k].z + vb[k].w*vb[k].w;
    }
    ss += __shfl_xor(ss, 16, 64);
    ss += __shfl_xor(ss, 32, 64);
    const float scale = 1.0f / (fmaxf(sqrtf(ss), 1e-12f) * TAU);
    bf16x8 afrag[16];
    #pragma unroll
    for (int k = 0; k < 16; ++k) {
        bf16x8 f;
        f[0] = (short)f2bf(va[k].x * scale); f[1] = (short)f2bf(va[k].y * scale);
        f[2] = (short)f2bf(va[k].z * scale); f[3] = (short)f2bf(va[k].w * scale);
        f[4] = (short)f2bf(vb[k].x * scale); f[5] = (short)f2bf(vb[k].y * scale);
        f[6] = (short)f2bf(vb[k].z * scale); f[7] = (short)f2bf(vb[k].w * scale);
        afrag[k] = f;
    }

    f32x4 acc[2][16];
    #pragma unroll
    for (int mt = 0; mt < 2; ++mt)
        #pragma unroll
        for (int nt = 0; nt < 16; ++nt) acc[mt][nt] = (f32x4){0.f,0.f,0.f,0.f};
    float dsum = 0.f;

    // ---- preload tile 0 -> buffer 0 (async global->LDS, 16B/lane)
    #pragma unroll
    for (int k = 0; k < 4; ++k) {
        glds16(rm_sw + (size_t)(k * 512 + tid) * 8, &s_rm[0][(k * 512 + tid) * 8]);
        glds16(t_sw  + (size_t)(k * 512 + tid) * 8, &s_ct[0][(k * 512 + tid) * 8]);
    }
    __syncthreads();

    const int pxc = (l15 * 4 + (q ^ ((l15 >> 1) & 3))) * 8;  // swizzled px chunk (u16 offset)
    const int swz = l15 & 7;

    for (int j = 0; j < NKT; ++j) {
        const int p = j & 1;
        const size_t nb = (size_t)((j + 1) & (NKT - 1)) * 16384;
        // prefetch next tile into the other buffer; drains at end-of-iter barrier
        #pragma unroll
        for (int k = 0; k < 4; ++k) {
            glds16(rm_sw + nb + (size_t)(k * 512 + tid) * 8, &s_rm[p ^ 1][(k * 512 + tid) * 8]);
            glds16(t_sw  + nb + (size_t)(k * 512 + tid) * 8, &s_ct[p ^ 1][(k * 512 + tid) * 8]);
        }

        // ---- S^T = C_tile · x_n^T  (A = cb-frag from LDS, B = x-frag regs)
        f32x4 s0 = (f32x4){0.f,0.f,0.f,0.f};
        f32x4 s1 = (f32x4){0.f,0.f,0.f,0.f};
        const unsigned short* srm = s_rm[p];
        #pragma unroll
        for (int kt = 0; kt < 16; ++kt) {
            int dc = (kt * 4 + q) ^ swz;
            bf16x8 bb0 = *(const bf16x8*)&srm[(l15 * 64 + dc) * 8];
            bf16x8 bb1 = *(const bf16x8*)&srm[((16 + l15) * 64 + dc) * 8];
            s0 = __builtin_amdgcn_mfma_f32_16x16x32_bf16(bb0, afrag[kt], s0, 0, 0, 0);
            s1 = __builtin_amdgcn_mfma_f32_16x16x32_bf16(bb1, afrag[kt], s1, 0, 0, 0);
        }

        // ---- P = exp(S^T): lane(q,l15) holds P[row l15][cb 4q+r] (s0) and [16+4q+r] (s1)
        const float e0 = __expf(s0[0]), e1 = __expf(s0[1]), e2 = __expf(s0[2]), e3 = __expf(s0[3]);
        const float f0 = __expf(s1[0]), f1 = __expf(s1[1]), f2 = __expf(s1[2]), f3 = __expf(s1[3]);
        float loc = ((e0 + e1) + (e2 + e3)) + ((f0 + f1) + (f2 + f3));
        // row-sum across quads without LDS (xor16 then xor32 via permlane swaps)
        float t16 = loc;
        pl16swapf(loc, t16); loc += t16;
        float t32 = loc;
        pl32swapf(loc, t32); loc += t32;
        dsum += loc;          // full row-l15 sum for this tile (replicated over quads)

        // ---- in-register transpose to PV A-layout: lane(q,l15) <- P[l15][8q+j], j=0..7
        // (HW-validated in round 2; transients die at the ds_write below, as in round 0)
        unsigned A0 = cvtpk(e0, e1), A1 = cvtpk(e2, e3);
        unsigned B0 = cvtpk(f0, f1), B1 = cvtpk(f2, f3);
        pl32swap(A0, B0); pl32swap(A1, B1);
        pl16swap(A0, B0); pl16swap(A1, B1);
        uint4 apv; apv.x = A0; apv.y = A1; apv.z = B0; apv.w = B1;
        *(uint4*)&s_px[w][pxc] = apv;
        __syncthreads();                         // B1: px visible

        bf16x8 ap0 = *(const bf16x8*)&s_px[pairA * 2][pxc];      // rows 0..15 of pair
        bf16x8 ap1 = *(const bf16x8*)&s_px[pairA * 2 + 1][pxc];  // rows 16..31 of pair

        // ---- O += P · C_tile over this wave's d-half (f=2 pairing)
        const unsigned short* sct = s_ct[p];
        #pragma unroll
        for (int nt = 0; nt < 16; ++nt) {
            int dd = dhalf * 256 + nt * 16 + l15;
            int c = (dd * 4 + q) ^ ((dd >> 1) & 7);
            bf16x8 bt = *(const bf16x8*)&sct[c * 8];
            acc[0][nt] = __builtin_amdgcn_mfma_f32_16x16x32_bf16(ap0, bt, acc[0][nt], 0, 0, 0);
            acc[1][nt] = __builtin_amdgcn_mfma_f32_16x16x32_bf16(ap1, bt, acc[1][nt], 0, 0, 0);
        }
        __syncthreads();                         // B2: buf reads done + prefetch drained
    }

    // ---- epilogue: exchange denominators, divide, store
    if (lane < 16) s_ds[w * 16 + lane] = dsum;
    __syncthreads();
    const int prow0 = pairA * 32;
    float* ob = out + ((size_t)blockIdx.x * BM + prow0) * D_DIM + dhalf * 256 + l15;
    #pragma unroll
    for (int mt = 0; mt < 2; ++mt) {
        #pragma unroll
        for (int r = 0; r < 4; ++r) {
            float inv = 1.0f / s_ds[prow0 + mt * 16 + q * 4 + r];
            #pragma unroll
            for (int nt = 0; nt < 16; ++nt) {
                ob[(size_t)(mt * 16 + q * 4 + r) * D_DIM + nt * 16] = acc[mt][nt][r] * inv;
            }
        }
    }
}

extern "C" void kernel_launch(void* const* d_in, const int* in_sizes, int n_in,
                              void* d_out, int out_size, void* d_ws, size_t ws_size,
                              hipStream_t stream) {
    const float* x  = (const float*)d_in[0];
    const float* cb = (const float*)d_in[1];
    unsigned short* rm_sw = (unsigned short*)d_ws;                       // 8 MB
    unsigned short* t_sw  = rm_sw + (size_t)K_CB * D_DIM;                // 8 MB
    float* outp = (float*)d_out;

    prep_codebook<<<NKT, 512, 0, stream>>>(cb, rm_sw, t_sw);
    cbmap_main<<<N_ROWS / BM, 512, 0, stream>>>(x, rm_sw, t_sw, outp);
}

// Round 4
// 775.925 us; speedup vs baseline: 1.9367x; 1.0229x over previous
//
#include <hip/hip_runtime.h>
#include <stdint.h>

#define N_ROWS 32768
#define K_CB   8192
#define D_DIM  512
#define TAU    0.07f
#define BM     128
#define BK     32
#define NKT    256

typedef __attribute__((ext_vector_type(8))) short bf16x8;
typedef __attribute__((ext_vector_type(4))) float f32x4;

__device__ __forceinline__ unsigned short f2bf(float f) {
    unsigned u = __builtin_bit_cast(unsigned, f);
    u += 0x7FFFu + ((u >> 16) & 1u);          // round-to-nearest-even
    return (unsigned short)(u >> 16);
}

__device__ __forceinline__ void glds16(const unsigned short* g, unsigned short* l) {
    __builtin_amdgcn_global_load_lds(
        (const __attribute__((address_space(1))) unsigned int*)g,
        (__attribute__((address_space(3))) unsigned int*)l, 16, 0, 0);
}

__device__ __forceinline__ unsigned cvtpk(float a, float b) {
    unsigned r;
    asm("v_cvt_pk_bf16_f32 %0, %1, %2" : "=v"(r) : "v"(a), "v"(b));
    return r;
}

__device__ __forceinline__ void pl32swapf(float& a, float& b) {
    asm volatile("v_permlane32_swap_b32 %0, %1" : "+v"(a), "+v"(b));
}
__device__ __forceinline__ void pl16swapf(float& a, float& b) {
    asm volatile("v_permlane16_swap_b32 %0, %1" : "+v"(a), "+v"(b));
}

// lgkm-only barrier (T4): px/sx visibility without draining the glds prefetch queue
__device__ __forceinline__ void barrier_lgkm() {
    asm volatile("s_waitcnt lgkmcnt(0)" ::: "memory");
    __builtin_amdgcn_s_barrier();
    __builtin_amdgcn_sched_barrier(0);
}

// codebook fp32 [K][512] -> two pre-swizzled bf16 arrays of 16B chunks per 32-row tile:
//  rm_sw: chunk c = cbl*64 + (dc ^ (cbl&7))        holds C[tile cb=cbl][d = dc*8 .. +7]
//  t_sw : chunk c = (d*4 + cbc) ^ ((d>>1)&7)       holds C[tile cb=cbc*8+e][d], e=0..7
__global__ __launch_bounds__(512) void prep_codebook(const float* __restrict__ cb,
                                                     unsigned short* __restrict__ rm_sw,
                                                     unsigned short* __restrict__ t_sw) {
    __shared__ unsigned short tile[32 * 512];     // row-major [cbl][d]
    const int j = blockIdx.x, t = threadIdx.x;
    const float2* src = (const float2*)(cb + (size_t)j * (BK * D_DIM));
    unsigned* t32 = (unsigned*)tile;
    #pragma unroll
    for (int it = 0; it < 16; ++it) {
        int e2 = it * 512 + t;
        float2 v = src[e2];
        t32[e2] = (unsigned)f2bf(v.x) | ((unsigned)f2bf(v.y) << 16);
    }
    __syncthreads();
    uint4* rmd = (uint4*)rm_sw + (size_t)j * 2048;
    uint4* twd = (uint4*)t_sw + (size_t)j * 2048;
    #pragma unroll
    for (int it = 0; it < 4; ++it) {
        int L = it * 512 + t;
        int cbl = L >> 6, dc = L & 63;
        int c = cbl * 64 + (dc ^ (cbl & 7));
        rmd[c] = *(const uint4*)&tile[cbl * 512 + dc * 8];
    }
    #pragma unroll
    for (int it = 0; it < 4; ++it) {
        int M = it * 512 + t;
        int d = M >> 2, cbc = M & 3;
        int c = (d * 4 + cbc) ^ ((d >> 1) & 7);
        unsigned short tmp[8];
        #pragma unroll
        for (int e = 0; e < 8; ++e) tmp[e] = tile[(cbc * 8 + e) * 512 + d];
        twd[c] = *(const uint4*)tmp;
    }
}

// K-split pairing: wave w = 2*pr + e holds the pair's 32 x-rows over d-half e (afrag
// unchanged at 64 VGPR), so each QK codebook read feeds 2 MFMAs (row-groups A/B).
// Partial S exchanged per cb-half via s_sx; P scattered to s_px via swizzled b64 writes.
__global__ __launch_bounds__(512, 2) void cbmap_main(const float* __restrict__ x,
                                                     const unsigned short* __restrict__ rm_sw,
                                                     const unsigned short* __restrict__ t_sw,
                                                     float* __restrict__ out) {
    __shared__ unsigned short s_rm[2][16384];   // 2 x 32 KB, swizzled cb-major tile
    __shared__ unsigned short s_ct[2][16384];   // 2 x 32 KB, swizzled d-major tile
    __shared__ float s_sx[4][2][2][256];        // 16 KB [pair][dst e][rowh][lane*4]
    __shared__ unsigned short s_px[4][1024];    // 8 KB  [pair][row*32 + blk'*8 + off]
    __shared__ float s_ds[2][128];              // norm partials / denom halves

    const int tid = threadIdx.x;
    const int w = tid >> 6, lane = tid & 63, l15 = lane & 15, q = lane >> 4;
    const int pr = w >> 1, e = w & 1;
    const int prow0 = blockIdx.x * BM + pr * 32;   // pair's 32 S-rows
    const int swz = l15 & 7;

    // ---- prologue: load 2 row-groups x own 256-d half; partial norms; exchange
    const float* xrowA = x + (size_t)(prow0 + l15) * D_DIM + e * 256 + q * 8;
    const float* xrowB = xrowA + 16 * D_DIM;
    float4 va[8], vb[8], vc[8], vd[8];
    float ssA = 0.f, ssB = 0.f;
    #pragma unroll
    for (int kt = 0; kt < 8; ++kt) {
        va[kt] = *(const float4*)(xrowA + kt * 32);
        vb[kt] = *(const float4*)(xrowA + kt * 32 + 4);
        vc[kt] = *(const float4*)(xrowB + kt * 32);
        vd[kt] = *(const float4*)(xrowB + kt * 32 + 4);
        ssA += va[kt].x*va[kt].x + va[kt].y*va[kt].y + va[kt].z*va[kt].z + va[kt].w*va[kt].w;
        ssA += vb[kt].x*vb[kt].x + vb[kt].y*vb[kt].y + vb[kt].z*vb[kt].z + vb[kt].w*vb[kt].w;
        ssB += vc[kt].x*vc[kt].x + vc[kt].y*vc[kt].y + vc[kt].z*vc[kt].z + vc[kt].w*vc[kt].w;
        ssB += vd[kt].x*vd[kt].x + vd[kt].y*vd[kt].y + vd[kt].z*vd[kt].z + vd[kt].w*vd[kt].w;
    }
    ssA += __shfl_xor(ssA, 16, 64);
    ssA += __shfl_xor(ssA, 32, 64);
    ssB += __shfl_xor(ssB, 16, 64);
    ssB += __shfl_xor(ssB, 32, 64);

    // preload tile 0 -> buffer 0 (async global->LDS, 16B/lane)
    #pragma unroll
    for (int k = 0; k < 4; ++k) {
        glds16(rm_sw + (size_t)(k * 512 + tid) * 8, &s_rm[0][(k * 512 + tid) * 8]);
        glds16(t_sw  + (size_t)(k * 512 + tid) * 8, &s_ct[0][(k * 512 + tid) * 8]);
    }
    if (lane < 16) {
        s_ds[e][pr * 32 + l15]      = ssA;
        s_ds[e][pr * 32 + 16 + l15] = ssB;
    }
    __syncthreads();                             // norm partials visible + preload drained
    const float totA = s_ds[0][pr * 32 + l15]      + s_ds[1][pr * 32 + l15];
    const float totB = s_ds[0][pr * 32 + 16 + l15] + s_ds[1][pr * 32 + 16 + l15];
    const float scaleA = 1.0f / (fmaxf(sqrtf(totA), 1e-12f) * TAU);
    const float scaleB = 1.0f / (fmaxf(sqrtf(totB), 1e-12f) * TAU);

    bf16x8 afragA[8], afragB[8];                 // B-frags: 32 pair rows x d-half e
    #pragma unroll
    for (int kt = 0; kt < 8; ++kt) {
        bf16x8 f;
        f[0] = (short)f2bf(va[kt].x * scaleA); f[1] = (short)f2bf(va[kt].y * scaleA);
        f[2] = (short)f2bf(va[kt].z * scaleA); f[3] = (short)f2bf(va[kt].w * scaleA);
        f[4] = (short)f2bf(vb[kt].x * scaleA); f[5] = (short)f2bf(vb[kt].y * scaleA);
        f[6] = (short)f2bf(vb[kt].z * scaleA); f[7] = (short)f2bf(vb[kt].w * scaleA);
        afragA[kt] = f;
        bf16x8 g;
        g[0] = (short)f2bf(vc[kt].x * scaleB); g[1] = (short)f2bf(vc[kt].y * scaleB);
        g[2] = (short)f2bf(vc[kt].z * scaleB); g[3] = (short)f2bf(vc[kt].w * scaleB);
        g[4] = (short)f2bf(vd[kt].x * scaleB); g[5] = (short)f2bf(vd[kt].y * scaleB);
        g[6] = (short)f2bf(vd[kt].z * scaleB); g[7] = (short)f2bf(vd[kt].w * scaleB);
        afragB[kt] = g;
    }

    f32x4 acc[2][16];
    #pragma unroll
    for (int mt = 0; mt < 2; ++mt)
        #pragma unroll
        for (int nt = 0; nt < 16; ++nt) acc[mt][nt] = (f32x4){0.f,0.f,0.f,0.f};
    float dsumA = 0.f, dsumB = 0.f;

    const int blkw = (((e * 2 + (q >> 1)) ^ (l15 & 3)) * 8) + (q & 1) * 4;  // px write (u16)
    const int blkr = (q ^ (l15 & 3)) * 8;                                   // px read (u16)
    unsigned short* pxp = &s_px[pr][0];
    float* sxw = &s_sx[pr][e ^ 1][0][lane * 4];
    const float* sxr = &s_sx[pr][e][0][lane * 4];

    for (int j = 0; j < NKT; ++j) {
        const int p = j & 1;
        const size_t nb = (size_t)((j + 1) & (NKT - 1)) * 16384;
        // prefetch next tile into the other buffer; drains at B2 (full __syncthreads)
        #pragma unroll
        for (int k = 0; k < 4; ++k) {
            glds16(rm_sw + nb + (size_t)(k * 512 + tid) * 8, &s_rm[p ^ 1][(k * 512 + tid) * 8]);
            glds16(t_sw  + nb + (size_t)(k * 512 + tid) * 8, &s_ct[p ^ 1][(k * 512 + tid) * 8]);
        }

        const unsigned short* srm = s_rm[p];
        // ---- QK phase 1: OTHER cb-half (for the partner), rows A+B share each read
        f32x4 t0 = (f32x4){0.f,0.f,0.f,0.f};
        f32x4 t1 = (f32x4){0.f,0.f,0.f,0.f};
        const int cbo = ((e ^ 1) * 16 + l15) * 64;
        #pragma unroll
        for (int kt = 0; kt < 8; ++kt) {
            int dc = (e * 32 + kt * 4 + q) ^ swz;
            bf16x8 bb = *(const bf16x8*)&srm[(cbo + dc) * 8];
            t0 = __builtin_amdgcn_mfma_f32_16x16x32_bf16(bb, afragA[kt], t0, 0, 0, 0);
            t1 = __builtin_amdgcn_mfma_f32_16x16x32_bf16(bb, afragB[kt], t1, 0, 0, 0);
        }
        *(f32x4*)sxw         = t0;               // -> partner, row-group A
        *(f32x4*)(sxw + 256) = t1;               // -> partner, row-group B

        // ---- QK phase 2: OWN cb-half
        f32x4 u0 = (f32x4){0.f,0.f,0.f,0.f};
        f32x4 u1 = (f32x4){0.f,0.f,0.f,0.f};
        const int cbe = (e * 16 + l15) * 64;
        #pragma unroll
        for (int kt = 0; kt < 8; ++kt) {
            int dc = (e * 32 + kt * 4 + q) ^ swz;
            bf16x8 bb = *(const bf16x8*)&srm[(cbe + dc) * 8];
            u0 = __builtin_amdgcn_mfma_f32_16x16x32_bf16(bb, afragA[kt], u0, 0, 0, 0);
            u1 = __builtin_amdgcn_mfma_f32_16x16x32_bf16(bb, afragB[kt], u1, 0, 0, 0);
        }
        barrier_lgkm();                          // Bsx: partials visible (prefetch in flight)

        const f32x4 r0 = *(const f32x4*)sxr;
        const f32x4 r1 = *(const f32x4*)(sxr + 256);
        // ---- full-d S for own cb-half; P = exp
        const float pA0 = __expf(u0[0] + r0[0]), pA1 = __expf(u0[1] + r0[1]);
        const float pA2 = __expf(u0[2] + r0[2]), pA3 = __expf(u0[3] + r0[3]);
        const float pB0 = __expf(u1[0] + r1[0]), pB1 = __expf(u1[1] + r1[1]);
        const float pB2 = __expf(u1[2] + r1[2]), pB3 = __expf(u1[3] + r1[3]);
        float locA = (pA0 + pA1) + (pA2 + pA3);
        float locB = (pB0 + pB1) + (pB2 + pB3);
        float tA = locA; pl16swapf(locA, tA); locA += tA;
        float uA = locA; pl32swapf(locA, uA); locA += uA;
        float tB = locB; pl16swapf(locB, tB); locB += tB;
        float uB = locB; pl32swapf(locB, uB); locB += uB;
        dsumA += locA;                           // half-sum (own cb-half), rows l15
        dsumB += locB;                           // half-sum, rows 16+l15

        // ---- pack + swizzled scatter to px: P[row][cb e*16+4q .. +3]
        uint2 wA; wA.x = cvtpk(pA0, pA1); wA.y = cvtpk(pA2, pA3);
        uint2 wB; wB.x = cvtpk(pB0, pB1); wB.y = cvtpk(pB2, pB3);
        *(uint2*)&pxp[l15 * 32 + blkw]        = wA;
        *(uint2*)&pxp[(16 + l15) * 32 + blkw] = wB;
        barrier_lgkm();                          // B1: px visible (prefetch in flight)

        bf16x8 ap0 = *(const bf16x8*)&pxp[l15 * 32 + blkr];        // rows 0..15 of pair
        bf16x8 ap1 = *(const bf16x8*)&pxp[(16 + l15) * 32 + blkr]; // rows 16..31 of pair

        // ---- O += P · C_tile over this wave's d-half (f=2 pairing)
        const unsigned short* sct = s_ct[p];
        #pragma unroll
        for (int nt = 0; nt < 16; ++nt) {
            int dd = e * 256 + nt * 16 + l15;
            int c = (dd * 4 + q) ^ ((dd >> 1) & 7);
            bf16x8 bt = *(const bf16x8*)&sct[c * 8];
            acc[0][nt] = __builtin_amdgcn_mfma_f32_16x16x32_bf16(ap0, bt, acc[0][nt], 0, 0, 0);
            acc[1][nt] = __builtin_amdgcn_mfma_f32_16x16x32_bf16(ap1, bt, acc[1][nt], 0, 0, 0);
        }
        __syncthreads();                         // B2: buf reads done + prefetch drained
    }

    // ---- epilogue: combine denominator halves across the pair, divide, store
    if (lane < 16) {
        s_ds[e][pr * 32 + l15]      = dsumA;
        s_ds[e][pr * 32 + 16 + l15] = dsumB;
    }
    __syncthreads();
    float* ob = out + (size_t)prow0 * D_DIM + e * 256 + l15;
    #pragma unroll
    for (int mt = 0; mt < 2; ++mt) {
        #pragma unroll
        for (int r = 0; r < 4; ++r) {
            int rl = pr * 32 + mt * 16 + q * 4 + r;
            float inv = 1.0f / (s_ds[0][rl] + s_ds[1][rl]);
            #pragma unroll
            for (int nt = 0; nt < 16; ++nt) {
                ob[(size_t)(mt * 16 + q * 4 + r) * D_DIM + nt * 16] = acc[mt][nt][r] * inv;
            }
        }
    }
}

extern "C" void kernel_launch(void* const* d_in, const int* in_sizes, int n_in,
                              void* d_out, int out_size, void* d_ws, size_t ws_size,
                              hipStream_t stream) {
    const float* x  = (const float*)d_in[0];
    const float* cb = (const float*)d_in[1];
    unsigned short* rm_sw = (unsigned short*)d_ws;                       // 8 MB
    unsigned short* t_sw  = rm_sw + (size_t)K_CB * D_DIM;                // 8 MB
    float* outp = (float*)d_out;

    prep_codebook<<<NKT, 512, 0, stream>>>(cb, rm_sw, t_sw);
    cbmap_main<<<N_ROWS / BM, 512, 0, stream>>>(x, rm_sw, t_sw, outp);
}